// Round 15
// baseline (1231.854 us; speedup 1.0000x reference)
//
#include <hip/hip_runtime.h>
#include <hip/hip_bf16.h>
#include <math.h>

#define NN 100000
#define HID 128
#define EPSV 1e-5f

typedef short bf16x8 __attribute__((ext_vector_type(8)));
typedef float f32x4 __attribute__((ext_vector_type(4)));
typedef unsigned short u16;

__device__ __forceinline__ u16 f2b(float f) {       // f32 -> bf16 RNE
  unsigned u = __builtin_bit_cast(unsigned, f);
  u += 0x7FFFu + ((u >> 16) & 1u);
  return (u16)(u >> 16);
}
__device__ __forceinline__ float b2f(u16 h) {
  unsigned u = ((unsigned)h) << 16;
  return __builtin_bit_cast(float, u);
}

#define AS1(p) ((__attribute__((address_space(1))) void*)(p))
#define AS3(p) ((__attribute__((address_space(3))) void*)(p))

// ---------------- fused init ----------------
static __global__ void k_init(float* __restrict__ degs, int n6,
                              int* __restrict__ cur, int nc,
                              float* __restrict__ stats, int ns) {
  int i = blockIdx.x * blockDim.x + threadIdx.x;
  if (i < n6) degs[i] = 0.f;
  if (i < nc) cur[i] = 0;
  if (i < ns) stats[i] = 0.f;
}

// ---------------- fused degree histogram ----------------
static __global__ void k_deg_all(const int* __restrict__ seq, const int* __restrict__ knn,
                                 const int* __restrict__ dis, int E0, int E1, int E2,
                                 float* __restrict__ sOut, float* __restrict__ sIn) {
  int e = blockIdx.x * blockDim.x + threadIdx.x;
  int rel, eo;
  const int *src, *dst;
  if (e < E0)            { rel = 0; eo = e;           src = seq; dst = seq + E0; }
  else if (e < E0 + E1)  { rel = 1; eo = e - E0;      src = knn; dst = knn + E1; }
  else if (e < E0+E1+E2) { rel = 2; eo = e - E0 - E1; src = dis; dst = dis + E2; }
  else return;
  atomicAdd(&sOut[(size_t)rel * NN + src[eo]], 1.f);
  atomicAdd(&sIn[(size_t)rel * NN + dst[eo]], 1.f);
}

// ---------------- exclusive scan (two-level); scan1 computes counts inline ----------------
static __global__ void k_scan1_c(const float* __restrict__ indegRaw, int* __restrict__ out,
                                 int* __restrict__ aux, int n) {   // n = NN+1
  __shared__ int s[256];
  int t = threadIdx.x, i = blockIdx.x * 256 + t;
  int v = 0;
  if (i < NN) v = (int)(indegRaw[i] + indegRaw[NN + i] + indegRaw[2 * NN + i]);
  s[t] = v; __syncthreads();
#pragma unroll
  for (int d = 1; d < 256; d <<= 1) {
    int x = (t >= d) ? s[t - d] : 0;
    __syncthreads();
    s[t] += x;
    __syncthreads();
  }
  if (i < n) out[i] = s[t] - v;
  if (t == 255) aux[blockIdx.x] = s[255];
}

static __global__ void k_scan2(int* __restrict__ aux, int nb) {
  __shared__ int s[256];
  __shared__ int carry;
  int t = threadIdx.x;
  if (t == 0) carry = 0;
  __syncthreads();
  for (int base = 0; base < nb; base += 256) {
    int i = base + t;
    int v = (i < nb) ? aux[i] : 0;
    s[t] = v; __syncthreads();
#pragma unroll
    for (int d = 1; d < 256; d <<= 1) {
      int x = (t >= d) ? s[t - d] : 0;
      __syncthreads();
      s[t] += x;
      __syncthreads();
    }
    int excl = s[t] - v + carry;
    if (i < nb) aux[i] = excl;
    int tot = s[255];
    __syncthreads();
    if (t == 0) carry += tot;
    __syncthreads();
  }
}

static __global__ void k_scan3(int* __restrict__ out, const int* __restrict__ aux, int n) {
  int i = blockIdx.x * 256 + threadIdx.x;
  if (i < n) out[i] += aux[blockIdx.x];
}

// ---------------- fused CSR fill: srt = (src<<2)|rel ----------------
static __global__ void k_fill_all(const int* __restrict__ seq, const int* __restrict__ knn,
                                  const int* __restrict__ dis, int E0, int E1, int E2,
                                  const int* __restrict__ off, int* __restrict__ cur,
                                  int* __restrict__ srt) {
  int e = blockIdx.x * blockDim.x + threadIdx.x;
  int rel, eo;
  const int *src, *dst;
  if (e < E0)            { rel = 0; eo = e;           src = seq; dst = seq + E0; }
  else if (e < E0 + E1)  { rel = 1; eo = e - E0;      src = knn; dst = knn + E1; }
  else if (e < E0+E1+E2) { rel = 2; eo = e - E0 - E1; src = dis; dst = dis + E2; }
  else return;
  int d = dst[eo];
  int p = off[d] + atomicAdd(&cur[d], 1);
  srt[p] = (src[eo] << 2) | rel;
}

// ---------------- fused weight convert ----------------
static __global__ void k_cvt_all(const float* __restrict__ W0, const float* __restrict__ W1,
                                 const float* __restrict__ fcW0, const float* __restrict__ fcW1,
                                 u16* __restrict__ Wt0, u16* __restrict__ Wt1,
                                 u16* __restrict__ fcWt0, u16* __restrict__ fcWt1) {
  const int N0 = 3 * 1280 * 128, N1 = 3 * 128 * 128, N2 = 128 * 128;
  int i = blockIdx.x * blockDim.x + threadIdx.x;
  if (i < N0) {
    int rel = i / (1280 * 128);
    int rem = i - rel * 1280 * 128;
    int k = rem >> 7, c = rem & 127;
    Wt0[((size_t)rel * 128 + c) * 1280 + k] = f2b(W0[i]);
  } else if (i < N0 + N1) {
    int j = i - N0;
    int rel = j / (128 * 128);
    int rem = j - rel * 128 * 128;
    int k = rem >> 7, c = rem & 127;
    Wt1[((size_t)rel * 128 + c) * 128 + k] = f2b(W1[j]);
  } else if (i < N0 + N1 + N2) {
    int j = i - N0 - N1;
    int k = j >> 7, c = j & 127;
    fcWt0[c * 128 + k] = f2b(fcW0[j]);
  } else if (i < N0 + N1 + 2 * N2) {
    int j = i - N0 - N1 - N2;
    int k = j >> 7, c = j & 127;
    fcWt1[c * 128 + k] = f2b(fcW1[j]);
  }
}

// ---------------- 8-wave 3-buffer pipelined fused MFMA GEMM (R12, best measured 300 us) ----------------
template<int K, bool AFFINE>
__global__ __launch_bounds__(512)
void k_gemm_pipe(const float* __restrict__ Af,
                 const u16* __restrict__ Wt,        // [384][K] bf16
                 const float* __restrict__ soutRaw, // [3][NN] raw out-degrees
                 const float* __restrict__ abg,     // [256] affine (AFFINE only)
                 u16* __restrict__ Y,               // [M][384] bf16
                 int M)
{
  constexpr int A_BYTES = 128 * 32 * 4;   // 16 KB f32 A
  constexpr int B_BYTES = 384 * 32 * 2;   // 24 KB bf16 B
  constexpr int BUF_U16 = (A_BYTES + B_BYTES) / 2;
  __shared__ u16 lds[3][BUF_U16];   // 120 KB
  __shared__ float abl[256];

  const int row0 = blockIdx.x * 128;
  const int t    = threadIdx.x;
  const int lane = t & 63;
  const int w    = t >> 6;          // 0..7
  const int wm   = w >> 2;          // 0..1
  const int wn   = w & 3;           // 0..3
  const int l15  = lane & 15, l4 = lane >> 4;
  const int kl   = l4 * 8;
  const int nk   = K / 32;

  int ar = row0 + w * 16 + l15;  if (ar >= M) ar = M - 1;

  const u16* gb0 = Wt + (size_t)(w * 48 +      l15) * K + kl;
  const u16* gb1 = Wt + (size_t)(w * 48 + 16 + l15) * K + kl;
  const u16* gb2 = Wt + (size_t)(w * 48 + 32 + l15) * K + kl;

  auto STAGE = [&](int buf, int k0) {
    u16* L = &lds[buf][0];
    const float* sa = Af + (size_t)ar * K + k0 + kl;
    __builtin_amdgcn_global_load_lds(AS1(sa),     AS3(L + (w * 2048) / 2),        16, 0, 0);
    __builtin_amdgcn_global_load_lds(AS1(sa + 4), AS3(L + (w * 2048 + 1024) / 2), 16, 0, 0);
    u16* Bd = L + A_BYTES / 2;
    __builtin_amdgcn_global_load_lds(AS1(gb0 + k0), AS3(Bd + (w * 3 + 0) * 512), 16, 0, 0);
    __builtin_amdgcn_global_load_lds(AS1(gb1 + k0), AS3(Bd + (w * 3 + 1) * 512), 16, 0, 0);
    __builtin_amdgcn_global_load_lds(AS1(gb2 + k0), AS3(Bd + (w * 3 + 2) * 512), 16, 0, 0);
  };

  if constexpr (AFFINE) {
    if (t < 256) abl[t] = abg[t];
    asm volatile("s_waitcnt lgkmcnt(0)" ::: "memory");
  }

  f32x4 acc[4][6];
#pragma unroll
  for (int m = 0; m < 4; ++m)
#pragma unroll
    for (int n = 0; n < 6; ++n) acc[m][n] = (f32x4){0.f, 0.f, 0.f, 0.f};

  STAGE(0, 0);
  if (nk > 1) STAGE(1, 32);

  for (int k = 0; k < nk; ++k) {
    if (k + 1 < nk) asm volatile("s_waitcnt vmcnt(5)" ::: "memory");
    else            asm volatile("s_waitcnt vmcnt(0)" ::: "memory");
    __builtin_amdgcn_sched_barrier(0);
    __builtin_amdgcn_s_barrier();
    __builtin_amdgcn_sched_barrier(0);

    if (k + 2 < nk) STAGE((k + 2) % 3, (k + 2) * 32);

    const int cur = k % 3;
    const int k0 = k * 32;
    bf16x8 a[4], b[6];
    {
      f32x4 s1, s2, s3, s4;
      if constexpr (AFFINE) {
        s1 = *(const f32x4*)&abl[k0 + kl];
        s2 = *(const f32x4*)&abl[k0 + kl + 4];
        s3 = *(const f32x4*)&abl[128 + k0 + kl];
        s4 = *(const f32x4*)&abl[128 + k0 + kl + 4];
      }
      const float* Al = (const float*)&lds[cur][0];
#pragma unroll
      for (int m = 0; m < 4; ++m) {
        f32x4 lo = *(const f32x4*)&Al[(wm * 4 + m) * 512 + lane * 4];
        f32x4 hi = *(const f32x4*)&Al[(wm * 4 + m) * 512 + 256 + lane * 4];
        union { bf16x8 v; u16 u[8]; } q;
#pragma unroll
        for (int j = 0; j < 4; ++j) {
          float vlo = lo[j], vhi = hi[j];
          if constexpr (AFFINE) {
            vlo = fmaf(vlo, s1[j], s3[j]);
            vhi = fmaf(vhi, s2[j], s4[j]);
          }
          q.u[j]     = __builtin_bit_cast(u16, __float2bfloat16(vlo));
          q.u[4 + j] = __builtin_bit_cast(u16, __float2bfloat16(vhi));
        }
        a[m] = q.v;
      }
      const u16* Bl = &lds[cur][A_BYTES / 2];
#pragma unroll
      for (int n = 0; n < 6; ++n) b[n] = *(const bf16x8*)&Bl[(wn * 6 + n) * 512 + lane * 8];
    }

#pragma unroll
    for (int m = 0; m < 4; ++m)
#pragma unroll
      for (int n = 0; n < 6; ++n)
        acc[m][n] = __builtin_amdgcn_mfma_f32_16x16x32_bf16(a[m], b[n], acc[m][n], 0, 0, 0);
  }

  // epilogue: C layout col=lane&15, row=(lane>>4)*4+reg
#pragma unroll
  for (int m = 0; m < 4; ++m) {
    const int rb = row0 + wm * 64 + m * 16 + l4 * 4;
#pragma unroll
    for (int j = 0; j < 4; ++j) {
      const int row = rb + j;
      if (row < M) {
        u16* yrow = Y + (size_t)row * 384;
#pragma unroll
        for (int n = 0; n < 6; ++n) {
          const int c = wn * 96 + n * 16;
          const float sc = rsqrtf(fmaxf(soutRaw[(size_t)(c >> 7) * NN + row], 1.f));
          yrow[c + l15] = f2b(acc[m][n][j] * sc);
        }
      }
    }
  }
}

// ---------------- fused gather + FC + BN-stats ----------------
// Block = 128 dst rows, 8 waves. Phase 1: wave w gathers nodes row0+w*16+i (i=0..15),
// lane holds cols {2l,2l+1}; packed u32 written to XOR-swizzled LDS tile
// (byte ^= (r&7)<<4 -> b128 frag reads land on distinct bank-quads, free 2-way).
// Phase 2: MFMA FC (acc @ fcW) + bias + ReLU + per-column stats. Kills the 51 MB
// acc16 global roundtrip and 2 dispatches.
static __global__ __launch_bounds__(512)
void k_gfc(const int* __restrict__ off, const int* __restrict__ srt,
           const float* __restrict__ sinRaw, const u16* __restrict__ Y,
           const float* __restrict__ b,
           const u16* __restrict__ Bt, const float* __restrict__ bias,
           float* __restrict__ Z, float* __restrict__ stats, int M)
{
  __shared__ unsigned Ablk[128 * 64];  // 32 KB, swizzled [r][64] u32
  __shared__ float sst[256];

  const int t    = threadIdx.x;
  const int lane = t & 63;
  const int w    = t >> 6;          // 0..7
  const int row0 = blockIdx.x * 128;

  if (t < 256) sst[t] = 0.f;

  // ---- phase 1: gather ----
  {
    const int c = lane * 2;
    const float bb0 = b[c]     + b[128 + c]     + b[256 + c];
    const float bb1 = b[c + 1] + b[128 + c + 1] + b[256 + c + 1];
    for (int i = 0; i < 16; ++i) {
      const int r = w * 16 + i;
      const int d = row0 + r;
      float v0 = 0.f, v1 = 0.f;
      if (d < M) {
        v0 = bb0; v1 = bb1;
        const float sc0 = rsqrtf(fmaxf(sinRaw[d], 1.f));
        const float sc1 = rsqrtf(fmaxf(sinRaw[NN + d], 1.f));
        const float sc2 = rsqrtf(fmaxf(sinRaw[2 * NN + d], 1.f));
        int j0 = off[d], j1 = off[d + 1];
        int j = j0;
        for (; j + 8 <= j1; j += 8) {
          unsigned uu[8];
          int rr[8];
#pragma unroll
          for (int q = 0; q < 8; ++q) {
            int tg = srt[j + q];
            rr[q] = tg & 3;
            uu[q] = *(const unsigned*)&Y[(size_t)(tg >> 2) * 384 + (size_t)rr[q] * 128 + c];
          }
#pragma unroll
          for (int q = 0; q < 8; ++q) {
            float s = (rr[q] == 0) ? sc0 : ((rr[q] == 1) ? sc1 : sc2);
            v0 = fmaf(b2f((u16)(uu[q] & 0xFFFFu)), s, v0);
            v1 = fmaf(b2f((u16)(uu[q] >> 16)), s, v1);
          }
        }
        for (; j < j1; ++j) {
          int tg = srt[j];
          int rl = tg & 3;
          unsigned u = *(const unsigned*)&Y[(size_t)(tg >> 2) * 384 + (size_t)rl * 128 + c];
          float s = (rl == 0) ? sc0 : ((rl == 1) ? sc1 : sc2);
          v0 = fmaf(b2f((u16)(u & 0xFFFFu)), s, v0);
          v1 = fmaf(b2f((u16)(u >> 16)), s, v1);
        }
      }
      unsigned o = (unsigned)f2b(v0) | ((unsigned)f2b(v1) << 16);
      unsigned ba = (unsigned)(r * 256 + lane * 4) ^ ((unsigned)(r & 7) << 4);
      Ablk[ba >> 2] = o;
    }
  }
  __syncthreads();

  // ---- phase 2: FC MFMA + stats ----
  const int wm = w >> 2, wn = w & 3;
  const int l15 = lane & 15, l4 = lane >> 4;
  const int kl = l4 * 8;

  bf16x8 br[2][4];
#pragma unroll
  for (int n = 0; n < 2; ++n)
#pragma unroll
    for (int ks = 0; ks < 4; ++ks)
      br[n][ks] = *(const bf16x8*)&Bt[(size_t)(wn * 32 + n * 16 + l15) * 128 + ks * 32 + kl];

  f32x4 acc[4][2];
#pragma unroll
  for (int m = 0; m < 4; ++m) { acc[m][0] = (f32x4){0,0,0,0}; acc[m][1] = (f32x4){0,0,0,0}; }

#pragma unroll
  for (int ks = 0; ks < 4; ++ks) {
#pragma unroll
    for (int m = 0; m < 4; ++m) {
      const int r = (wm * 4 + m) * 16 + l15;
      unsigned ba = (unsigned)(r * 256 + ks * 64 + l4 * 16) ^ ((unsigned)(r & 7) << 4);
      bf16x8 a = *(const bf16x8*)((const char*)Ablk + ba);
      acc[m][0] = __builtin_amdgcn_mfma_f32_16x16x32_bf16(a, br[0][ks], acc[m][0], 0, 0, 0);
      acc[m][1] = __builtin_amdgcn_mfma_f32_16x16x32_bf16(a, br[1][ks], acc[m][1], 0, 0, 0);
    }
  }

  float ps[2] = {0.f, 0.f}, ps2[2] = {0.f, 0.f};
#pragma unroll
  for (int m = 0; m < 4; ++m) {
    const int rb = row0 + wm * 64 + m * 16 + l4 * 4;
#pragma unroll
    for (int j = 0; j < 4; ++j) {
      const int row = rb + j;
      const bool ok = row < M;
#pragma unroll
      for (int n = 0; n < 2; ++n) {
        const int cc = wn * 32 + n * 16 + l15;
        float v = ok ? fmaxf(acc[m][n][j] + bias[cc], 0.f) : 0.f;
        if (ok) Z[(size_t)row * 128 + cc] = v;
        ps[n]  += v;
        ps2[n] += v * v;
      }
    }
  }
#pragma unroll
  for (int n = 0; n < 2; ++n) {
    ps[n]  += __shfl_xor(ps[n], 16);  ps[n]  += __shfl_xor(ps[n], 32);
    ps2[n] += __shfl_xor(ps2[n], 16); ps2[n] += __shfl_xor(ps2[n], 32);
  }
  if (l4 == 0) {
#pragma unroll
    for (int n = 0; n < 2; ++n) {
      const int cc = wn * 32 + n * 16 + l15;
      atomicAdd(&sst[cc], ps[n]);
      atomicAdd(&sst[128 + cc], ps2[n]);
    }
  }
  __syncthreads();
  if (t < 256) atomicAdd(&stats[t], sst[t]);
}

// ---------------- BatchNorm finalize / final apply ----------------
static __global__ void k_bn_finalize(const float* __restrict__ stats, int M,
                                     const float* __restrict__ g, const float* __restrict__ beta,
                                     float* __restrict__ ab) {
  int j = threadIdx.x;  // 128
  float m  = stats[j] / (float)M;
  float v  = stats[128 + j] / (float)M - m * m;
  float inv = rsqrtf(v + EPSV) * g[j];
  ab[j]       = inv;
  ab[128 + j] = beta[j] - m * inv;
}

static __global__ void k_bn_apply_f32(const float* __restrict__ Z, const float* __restrict__ ab,
                                      float* __restrict__ out, int n) {
  int i = blockIdx.x * blockDim.x + threadIdx.x;
  if (i < n) {
    int j = i & 127;
    out[i] = Z[i] * ab[j] + ab[128 + j];
  }
}

extern "C" void kernel_launch(void* const* d_in, const int* in_sizes, int n_in,
                              void* d_out, int out_size, void* d_ws, size_t ws_size,
                              hipStream_t stream)
{
  const float* x    = (const float*)d_in[0];
  const int*   seq  = (const int*)d_in[1];
  const int*   knn  = (const int*)d_in[2];
  const int*   dis  = (const int*)d_in[3];
  const float* W0   = (const float*)d_in[4];
  const float* b0   = (const float*)d_in[5];
  const float* fcW0 = (const float*)d_in[6];
  const float* fcb0 = (const float*)d_in[7];
  const float* g0   = (const float*)d_in[8];
  const float* be0  = (const float*)d_in[9];
  const float* W1   = (const float*)d_in[10];
  const float* b1   = (const float*)d_in[11];
  const float* fcW1 = (const float*)d_in[12];
  const float* fcb1 = (const float*)d_in[13];
  const float* g1   = (const float*)d_in[14];
  const float* be1  = (const float*)d_in[15];

  const int E0 = in_sizes[1] / 2, E1 = in_sizes[2] / 2, E2 = in_sizes[3] / 2;
  const int ETOT = E0 + E1 + E2;

  const size_t N = NN;

  float* ws    = (float*)d_ws;
  float* sOut  = ws;                        // 3N raw out-degrees
  float* sIn   = sOut + 3 * N;              // 3N raw in-degrees
  float* stats = sIn + 3 * N;               // 512
  float* ab0   = stats + 512;               // 256
  float* ab1   = ab0 + 256;                 // 256
  u16*   Y     = (u16*)(ab1 + 256);         // N*384 bf16
  float* Z     = (float*)(Y + N * 384);     // N*128 f32
  u16*   Wt0   = (u16*)(Z + N * 128);       // 3*128*1280
  u16*   Wt1   = Wt0 + 3 * 128 * 1280;      // 3*128*128
  u16*   fcWt0 = Wt1 + 3 * 128 * 128;       // 128*128
  u16*   fcWt1 = fcWt0 + 128 * 128;         // 128*128
  int*   off   = (int*)(fcWt1 + 128 * 128); // N+1
  int*   aux   = off + (NN + 1);            // scan aux
  int*   cur   = aux + 1536;                // N
  int*   srt   = cur + NN;                  // ETOT

  const int NT = (NN + 127) / 128;

  // ---- preprocessing ----
  k_init<<<(6 * NN + 255) / 256, 256, 0, stream>>>(sOut, 6 * NN, cur, NN, stats, 512);
  k_deg_all<<<(ETOT + 255) / 256, 256, 0, stream>>>(seq, knn, dis, E0, E1, E2, sOut, sIn);

  const int nsc = NN + 1;
  const int nb  = (nsc + 255) / 256;
  k_scan1_c<<<nb, 256, 0, stream>>>(sIn, off, aux, nsc);
  k_scan2<<<1, 256, 0, stream>>>(aux, nb);
  k_scan3<<<nb, 256, 0, stream>>>(off, aux, nsc);

  k_fill_all<<<(ETOT + 255) / 256, 256, 0, stream>>>(seq, knn, dis, E0, E1, E2, off, cur, srt);

  const int CVT_TOT = 3 * 1280 * 128 + 3 * 128 * 128 + 2 * 128 * 128;
  k_cvt_all<<<(CVT_TOT + 255) / 256, 256, 0, stream>>>(W0, W1, fcW0, fcW1, Wt0, Wt1, fcWt0, fcWt1);

  // ---- layer 0 ----
  k_gemm_pipe<1280, false><<<NT, 512, 0, stream>>>(x, Wt0, sOut, nullptr, Y, NN);
  k_gfc<<<NT, 512, 0, stream>>>(off, srt, sIn, Y, b0, fcWt0, fcb0, Z, stats, NN);
  k_bn_finalize<<<1, 128, 0, stream>>>(stats, NN, g0, be0, ab0);

  // ---- layer 1 (BN-apply of layer 0 fused into gemm's cvt) ----
  k_gemm_pipe<128, true><<<NT, 512, 0, stream>>>(Z, Wt1, sOut, ab0, Y, NN);
  k_gfc<<<NT, 512, 0, stream>>>(off, srt, sIn, Y, b1, fcWt1, fcb1, Z, stats + 256, NN);
  k_bn_finalize<<<1, 128, 0, stream>>>(stats + 256, NN, g1, be1, ab1);
  k_bn_apply_f32<<<(NN * HID + 255) / 256, 256, 0, stream>>>(Z, ab1, (float*)d_out, NN * HID);
}

// Round 16
// 1161.578 us; speedup vs baseline: 1.0605x; 1.0605x over previous
//
#include <hip/hip_runtime.h>
#include <hip/hip_bf16.h>
#include <math.h>

#define NN 100000
#define HID 128
#define EPSV 1e-5f

typedef short bf16x8 __attribute__((ext_vector_type(8)));
typedef float f32x4 __attribute__((ext_vector_type(4)));
typedef unsigned short u16;

__device__ __forceinline__ u16 f2b(float f) {       // f32 -> bf16 RNE
  unsigned u = __builtin_bit_cast(unsigned, f);
  u += 0x7FFFu + ((u >> 16) & 1u);
  return (u16)(u >> 16);
}
__device__ __forceinline__ float b2f(u16 h) {
  unsigned u = ((unsigned)h) << 16;
  return __builtin_bit_cast(float, u);
}

#define AS1(p) ((__attribute__((address_space(1))) void*)(p))
#define AS3(p) ((__attribute__((address_space(3))) void*)(p))

// ---------------- fused init: zero degree arrays + stats ----------------
static __global__ void k_init(float* __restrict__ degs, int n6,
                              float* __restrict__ stats, int ns) {
  int i = blockIdx.x * blockDim.x + threadIdx.x;
  if (i < n6) degs[i] = 0.f;
  if (i < ns) stats[i] = 0.f;
}

// ---------------- fused degree histogram ----------------
static __global__ void k_deg_all(const int* __restrict__ seq, const int* __restrict__ knn,
                                 const int* __restrict__ dis, int E0, int E1, int E2,
                                 float* __restrict__ sOut, float* __restrict__ sIn) {
  int e = blockIdx.x * blockDim.x + threadIdx.x;
  int rel, eo;
  const int *src, *dst;
  if (e < E0)            { rel = 0; eo = e;           src = seq; dst = seq + E0; }
  else if (e < E0 + E1)  { rel = 1; eo = e - E0;      src = knn; dst = knn + E1; }
  else if (e < E0+E1+E2) { rel = 2; eo = e - E0 - E1; src = dis; dst = dis + E2; }
  else return;
  atomicAdd(&sOut[(size_t)rel * NN + src[eo]], 1.f);
  atomicAdd(&sIn[(size_t)rel * NN + dst[eo]], 1.f);
}

// ---------------- exclusive scan (two-level); scan1 computes counts inline ----------------
static __global__ void k_scan1_c(const float* __restrict__ indegRaw, int* __restrict__ out,
                                 int* __restrict__ aux, int n) {   // n = NN+1
  __shared__ int s[256];
  int t = threadIdx.x, i = blockIdx.x * 256 + t;
  int v = 0;
  if (i < NN) v = (int)(indegRaw[i] + indegRaw[NN + i] + indegRaw[2 * NN + i]);
  s[t] = v; __syncthreads();
#pragma unroll
  for (int d = 1; d < 256; d <<= 1) {
    int x = (t >= d) ? s[t - d] : 0;
    __syncthreads();
    s[t] += x;
    __syncthreads();
  }
  if (i < n) out[i] = s[t] - v;
  if (t == 255) aux[blockIdx.x] = s[255];
}

static __global__ void k_scan2(int* __restrict__ aux, int nb) {
  __shared__ int s[256];
  __shared__ int carry;
  int t = threadIdx.x;
  if (t == 0) carry = 0;
  __syncthreads();
  for (int base = 0; base < nb; base += 256) {
    int i = base + t;
    int v = (i < nb) ? aux[i] : 0;
    s[t] = v; __syncthreads();
#pragma unroll
    for (int d = 1; d < 256; d <<= 1) {
      int x = (t >= d) ? s[t - d] : 0;
      __syncthreads();
      s[t] += x;
      __syncthreads();
    }
    int excl = s[t] - v + carry;
    if (i < nb) aux[i] = excl;
    int tot = s[255];
    __syncthreads();
    if (t == 0) carry += tot;
    __syncthreads();
  }
}

// scan3 also emits off2 (mutable cursor copy used directly by fill)
static __global__ void k_scan3(int* __restrict__ out, int* __restrict__ off2,
                               const int* __restrict__ aux, int n) {
  int i = blockIdx.x * 256 + threadIdx.x;
  if (i < n) {
    int v = out[i] + aux[blockIdx.x];
    out[i] = v;
    if (i < NN) off2[i] = v;
  }
}

// ---------------- fused CSR fill: srt[off2[dst]++] = (src<<2)|rel ----------------
static __global__ void k_fill_all(const int* __restrict__ seq, const int* __restrict__ knn,
                                  const int* __restrict__ dis, int E0, int E1, int E2,
                                  int* __restrict__ off2, int* __restrict__ srt) {
  int e = blockIdx.x * blockDim.x + threadIdx.x;
  int rel, eo;
  const int *src, *dst;
  if (e < E0)            { rel = 0; eo = e;           src = seq; dst = seq + E0; }
  else if (e < E0 + E1)  { rel = 1; eo = e - E0;      src = knn; dst = knn + E1; }
  else if (e < E0+E1+E2) { rel = 2; eo = e - E0 - E1; src = dis; dst = dis + E2; }
  else return;
  int p = atomicAdd(&off2[dst[eo]], 1);
  srt[p] = (src[eo] << 2) | rel;
}

// ---------------- fused weight convert ----------------
static __global__ void k_cvt_all(const float* __restrict__ W0, const float* __restrict__ W1,
                                 const float* __restrict__ fcW0, const float* __restrict__ fcW1,
                                 u16* __restrict__ Wt0, u16* __restrict__ Wt1,
                                 u16* __restrict__ fcWt0, u16* __restrict__ fcWt1) {
  const int N0 = 3 * 1280 * 128, N1 = 3 * 128 * 128, N2 = 128 * 128;
  int i = blockIdx.x * blockDim.x + threadIdx.x;
  if (i < N0) {
    int rel = i / (1280 * 128);
    int rem = i - rel * 1280 * 128;
    int k = rem >> 7, c = rem & 127;
    Wt0[((size_t)rel * 128 + c) * 1280 + k] = f2b(W0[i]);
  } else if (i < N0 + N1) {
    int j = i - N0;
    int rel = j / (128 * 128);
    int rem = j - rel * 128 * 128;
    int k = rem >> 7, c = rem & 127;
    Wt1[((size_t)rel * 128 + c) * 128 + k] = f2b(W1[j]);
  } else if (i < N0 + N1 + N2) {
    int j = i - N0 - N1;
    int k = j >> 7, c = j & 127;
    fcWt0[c * 128 + k] = f2b(fcW0[j]);
  } else if (i < N0 + N1 + 2 * N2) {
    int j = i - N0 - N1 - N2;
    int k = j >> 7, c = j & 127;
    fcWt1[c * 128 + k] = f2b(fcW1[j]);
  }
}

// ---------------- 8-wave 3-buffer pipelined fused MFMA GEMM (R12, best measured ~298 us) ----------------
// AFFINE (layer 1): BN affine computed in-prologue from stats/g/beta (kills bn_finalize dispatch),
// applied during the f32->bf16 cvt; table in LDS.
template<int K, bool AFFINE>
__global__ __launch_bounds__(512)
void k_gemm_pipe(const float* __restrict__ Af,
                 const u16* __restrict__ Wt,        // [384][K] bf16
                 const float* __restrict__ soutRaw, // [3][NN] raw out-degrees
                 const float* __restrict__ stats,   // [256] (AFFINE only)
                 const float* __restrict__ gamma,   // [128] (AFFINE only)
                 const float* __restrict__ beta,    // [128] (AFFINE only)
                 u16* __restrict__ Y,               // [M][384] bf16
                 int M)
{
  constexpr int A_BYTES = 128 * 32 * 4;   // 16 KB f32 A
  constexpr int B_BYTES = 384 * 32 * 2;   // 24 KB bf16 B
  constexpr int BUF_U16 = (A_BYTES + B_BYTES) / 2;
  __shared__ u16 lds[3][BUF_U16];   // 120 KB
  __shared__ float abl[256];

  const int row0 = blockIdx.x * 128;
  const int t    = threadIdx.x;
  const int lane = t & 63;
  const int w    = t >> 6;          // 0..7
  const int wm   = w >> 2;          // 0..1
  const int wn   = w & 3;           // 0..3
  const int l15  = lane & 15, l4 = lane >> 4;
  const int kl   = l4 * 8;
  const int nk   = K / 32;

  int ar = row0 + w * 16 + l15;  if (ar >= M) ar = M - 1;

  const u16* gb0 = Wt + (size_t)(w * 48 +      l15) * K + kl;
  const u16* gb1 = Wt + (size_t)(w * 48 + 16 + l15) * K + kl;
  const u16* gb2 = Wt + (size_t)(w * 48 + 32 + l15) * K + kl;

  auto STAGE = [&](int buf, int k0) {
    u16* L = &lds[buf][0];
    const float* sa = Af + (size_t)ar * K + k0 + kl;
    __builtin_amdgcn_global_load_lds(AS1(sa),     AS3(L + (w * 2048) / 2),        16, 0, 0);
    __builtin_amdgcn_global_load_lds(AS1(sa + 4), AS3(L + (w * 2048 + 1024) / 2), 16, 0, 0);
    u16* Bd = L + A_BYTES / 2;
    __builtin_amdgcn_global_load_lds(AS1(gb0 + k0), AS3(Bd + (w * 3 + 0) * 512), 16, 0, 0);
    __builtin_amdgcn_global_load_lds(AS1(gb1 + k0), AS3(Bd + (w * 3 + 1) * 512), 16, 0, 0);
    __builtin_amdgcn_global_load_lds(AS1(gb2 + k0), AS3(Bd + (w * 3 + 2) * 512), 16, 0, 0);
  };

  if constexpr (AFFINE) {
    if (t < 128) {
      const float invM = 1.f / (float)M;
      float mu  = stats[t] * invM;
      float var = stats[128 + t] * invM - mu * mu;
      float inv = rsqrtf(var + EPSV) * gamma[t];
      abl[t]       = inv;
      abl[128 + t] = beta[t] - mu * inv;
    }
    asm volatile("s_waitcnt lgkmcnt(0)" ::: "memory");
  }

  f32x4 acc[4][6];
#pragma unroll
  for (int m = 0; m < 4; ++m)
#pragma unroll
    for (int n = 0; n < 6; ++n) acc[m][n] = (f32x4){0.f, 0.f, 0.f, 0.f};

  STAGE(0, 0);
  if (nk > 1) STAGE(1, 32);

  for (int k = 0; k < nk; ++k) {
    if (k + 1 < nk) asm volatile("s_waitcnt vmcnt(5)" ::: "memory");
    else            asm volatile("s_waitcnt vmcnt(0)" ::: "memory");
    __builtin_amdgcn_sched_barrier(0);
    __builtin_amdgcn_s_barrier();
    __builtin_amdgcn_sched_barrier(0);

    if (k + 2 < nk) STAGE((k + 2) % 3, (k + 2) * 32);

    const int cur = k % 3;
    const int k0 = k * 32;
    bf16x8 a[4], b[6];
    {
      f32x4 s1, s2, s3, s4;
      if constexpr (AFFINE) {
        s1 = *(const f32x4*)&abl[k0 + kl];
        s2 = *(const f32x4*)&abl[k0 + kl + 4];
        s3 = *(const f32x4*)&abl[128 + k0 + kl];
        s4 = *(const f32x4*)&abl[128 + k0 + kl + 4];
      }
      const float* Al = (const float*)&lds[cur][0];
#pragma unroll
      for (int m = 0; m < 4; ++m) {
        f32x4 lo = *(const f32x4*)&Al[(wm * 4 + m) * 512 + lane * 4];
        f32x4 hi = *(const f32x4*)&Al[(wm * 4 + m) * 512 + 256 + lane * 4];
        union { bf16x8 v; u16 u[8]; } q;
#pragma unroll
        for (int j = 0; j < 4; ++j) {
          float vlo = lo[j], vhi = hi[j];
          if constexpr (AFFINE) {
            vlo = fmaf(vlo, s1[j], s3[j]);
            vhi = fmaf(vhi, s2[j], s4[j]);
          }
          q.u[j]     = __builtin_bit_cast(u16, __float2bfloat16(vlo));
          q.u[4 + j] = __builtin_bit_cast(u16, __float2bfloat16(vhi));
        }
        a[m] = q.v;
      }
      const u16* Bl = &lds[cur][A_BYTES / 2];
#pragma unroll
      for (int n = 0; n < 6; ++n) b[n] = *(const bf16x8*)&Bl[(wn * 6 + n) * 512 + lane * 8];
    }

#pragma unroll
    for (int m = 0; m < 4; ++m)
#pragma unroll
      for (int n = 0; n < 6; ++n)
        acc[m][n] = __builtin_amdgcn_mfma_f32_16x16x32_bf16(a[m], b[n], acc[m][n], 0, 0, 0);
  }

  // epilogue: C layout col=lane&15, row=(lane>>4)*4+reg
#pragma unroll
  for (int m = 0; m < 4; ++m) {
    const int rb = row0 + wm * 64 + m * 16 + l4 * 4;
#pragma unroll
    for (int j = 0; j < 4; ++j) {
      const int row = rb + j;
      if (row < M) {
        u16* yrow = Y + (size_t)row * 384;
#pragma unroll
        for (int n = 0; n < 6; ++n) {
          const int c = wn * 96 + n * 16;
          const float sc = rsqrtf(fmaxf(soutRaw[(size_t)(c >> 7) * NN + row], 1.f));
          yrow[c + l15] = f2b(acc[m][n][j] * sc);
        }
      }
    }
  }
}

// ---------------- unified CSR gather (R12 structure: 1 wave/node, unroll 8 + 4) ----------------
static __global__ __launch_bounds__(256)
void k_gather(const int* __restrict__ off, const int* __restrict__ srt,
              const float* __restrict__ sinRaw, const u16* __restrict__ Y,
              const float* __restrict__ b, u16* __restrict__ acc16)
{
  int d = blockIdx.x * 4 + (threadIdx.x >> 6);
  if (d >= NN) return;
  int c = (threadIdx.x & 63) * 2;
  float v0 = b[c]     + b[128 + c]     + b[256 + c];
  float v1 = b[c + 1] + b[128 + c + 1] + b[256 + c + 1];
  const float sc0 = rsqrtf(fmaxf(sinRaw[d], 1.f));
  const float sc1 = rsqrtf(fmaxf(sinRaw[NN + d], 1.f));
  const float sc2 = rsqrtf(fmaxf(sinRaw[2 * NN + d], 1.f));
  int j0 = off[d], j1 = off[d + 1];
  int j = j0;
  for (; j + 8 <= j1; j += 8) {
    unsigned uu[8];
    int rr[8];
#pragma unroll
    for (int q = 0; q < 8; ++q) {
      int tg = srt[j + q];
      rr[q] = tg & 3;
      uu[q] = *(const unsigned*)&Y[(size_t)(tg >> 2) * 384 + (size_t)rr[q] * 128 + c];
    }
#pragma unroll
    for (int q = 0; q < 8; ++q) {
      float s = (rr[q] == 0) ? sc0 : ((rr[q] == 1) ? sc1 : sc2);
      v0 = fmaf(b2f((u16)(uu[q] & 0xFFFFu)), s, v0);
      v1 = fmaf(b2f((u16)(uu[q] >> 16)), s, v1);
    }
  }
  if (j + 4 <= j1) {
    unsigned uu[4];
    int rr[4];
#pragma unroll
    for (int q = 0; q < 4; ++q) {
      int tg = srt[j + q];
      rr[q] = tg & 3;
      uu[q] = *(const unsigned*)&Y[(size_t)(tg >> 2) * 384 + (size_t)rr[q] * 128 + c];
    }
#pragma unroll
    for (int q = 0; q < 4; ++q) {
      float s = (rr[q] == 0) ? sc0 : ((rr[q] == 1) ? sc1 : sc2);
      v0 = fmaf(b2f((u16)(uu[q] & 0xFFFFu)), s, v0);
      v1 = fmaf(b2f((u16)(uu[q] >> 16)), s, v1);
    }
    j += 4;
  }
  for (; j < j1; ++j) {
    int tg = srt[j];
    int r = tg & 3;
    unsigned u = *(const unsigned*)&Y[(size_t)(tg >> 2) * 384 + (size_t)r * 128 + c];
    float s = (r == 0) ? sc0 : ((r == 1) ? sc1 : sc2);
    v0 = fmaf(b2f((u16)(u & 0xFFFFu)), s, v0);
    v1 = fmaf(b2f((u16)(u >> 16)), s, v1);
  }
  unsigned o = (unsigned)f2b(v0) | ((unsigned)f2b(v1) << 16);
  *(unsigned*)&acc16[(size_t)d * 128 + c] = o;
}

// ---------------- FC (128x128) via MFMA + fused BN-stats ----------------
static __global__ __launch_bounds__(512)
void k_fc_mfma(const u16* __restrict__ A,      // [M][128] bf16
               const u16* __restrict__ Bt,     // [128][128] bf16 (row=outcol)
               const float* __restrict__ bias,
               float* __restrict__ Z, float* __restrict__ stats, int M)
{
  __shared__ u16 Ab[4][4096];   // 32 KB
  __shared__ float sst[256];

  const int row0 = blockIdx.x * 128;
  const int t    = threadIdx.x;
  const int lane = t & 63;
  const int w    = t >> 6;
  const int wm   = w >> 2;          // 0..1
  const int wn   = w & 3;           // 0..3
  const int l15  = lane & 15, l4 = lane >> 4;
  const int kl   = l4 * 8;

  if (t < 256) sst[t] = 0.f;

  int ar = row0 + w * 16 + l15;  if (ar >= M) ar = M - 1;

  bf16x8 br[2][4];
#pragma unroll
  for (int n = 0; n < 2; ++n)
#pragma unroll
    for (int ks = 0; ks < 4; ++ks)
      br[n][ks] = *(const bf16x8*)&Bt[(size_t)(wn * 32 + n * 16 + l15) * 128 + ks * 32 + kl];

#pragma unroll
  for (int ks = 0; ks < 4; ++ks)
    __builtin_amdgcn_global_load_lds(AS1(A + (size_t)ar * 128 + ks * 32 + kl),
                                     AS3(&Ab[ks][w * 512]), 16, 0, 0);

  asm volatile("s_waitcnt vmcnt(0)" ::: "memory");
  __syncthreads();

  f32x4 acc[4][2];
#pragma unroll
  for (int m = 0; m < 4; ++m) { acc[m][0] = (f32x4){0,0,0,0}; acc[m][1] = (f32x4){0,0,0,0}; }

#pragma unroll
  for (int ks = 0; ks < 4; ++ks) {
#pragma unroll
    for (int m = 0; m < 4; ++m) {
      bf16x8 a = *(const bf16x8*)&Ab[ks][(wm * 4 + m) * 512 + lane * 8];
      acc[m][0] = __builtin_amdgcn_mfma_f32_16x16x32_bf16(a, br[0][ks], acc[m][0], 0, 0, 0);
      acc[m][1] = __builtin_amdgcn_mfma_f32_16x16x32_bf16(a, br[1][ks], acc[m][1], 0, 0, 0);
    }
  }

  float ps[2] = {0.f, 0.f}, ps2[2] = {0.f, 0.f};
#pragma unroll
  for (int m = 0; m < 4; ++m) {
    const int rb = row0 + wm * 64 + m * 16 + l4 * 4;
#pragma unroll
    for (int j = 0; j < 4; ++j) {
      const int row = rb + j;
      const bool ok = row < M;
#pragma unroll
      for (int n = 0; n < 2; ++n) {
        const int cc = wn * 32 + n * 16 + l15;
        float v = ok ? fmaxf(acc[m][n][j] + bias[cc], 0.f) : 0.f;
        if (ok) Z[(size_t)row * 128 + cc] = v;
        ps[n]  += v;
        ps2[n] += v * v;
      }
    }
  }
#pragma unroll
  for (int n = 0; n < 2; ++n) {
    ps[n]  += __shfl_xor(ps[n], 16);  ps[n]  += __shfl_xor(ps[n], 32);
    ps2[n] += __shfl_xor(ps2[n], 16); ps2[n] += __shfl_xor(ps2[n], 32);
  }
  if (l4 == 0) {
#pragma unroll
    for (int n = 0; n < 2; ++n) {
      const int cc = wn * 32 + n * 16 + l15;
      atomicAdd(&sst[cc], ps[n]);
      atomicAdd(&sst[128 + cc], ps2[n]);
    }
  }
  __syncthreads();
  if (t < 256) atomicAdd(&stats[t], sst[t]);
}

// ---------------- final BN apply (affine computed per-thread from stats) ----------------
static __global__ void k_bn_apply_f32(const float* __restrict__ Z,
                                      const float* __restrict__ stats,
                                      const float* __restrict__ gamma,
                                      const float* __restrict__ beta,
                                      float* __restrict__ out, int n, int M) {
  int i = blockIdx.x * blockDim.x + threadIdx.x;
  if (i < n) {
    int j = i & 127;
    const float invM = 1.f / (float)M;
    float mu  = stats[j] * invM;
    float var = stats[128 + j] * invM - mu * mu;
    float inv = rsqrtf(var + EPSV) * gamma[j];
    out[i] = (Z[i] - mu) * inv + beta[j];
  }
}

extern "C" void kernel_launch(void* const* d_in, const int* in_sizes, int n_in,
                              void* d_out, int out_size, void* d_ws, size_t ws_size,
                              hipStream_t stream)
{
  const float* x    = (const float*)d_in[0];
  const int*   seq  = (const int*)d_in[1];
  const int*   knn  = (const int*)d_in[2];
  const int*   dis  = (const int*)d_in[3];
  const float* W0   = (const float*)d_in[4];
  const float* b0   = (const float*)d_in[5];
  const float* fcW0 = (const float*)d_in[6];
  const float* fcb0 = (const float*)d_in[7];
  const float* g0   = (const float*)d_in[8];
  const float* be0  = (const float*)d_in[9];
  const float* W1   = (const float*)d_in[10];
  const float* b1   = (const float*)d_in[11];
  const float* fcW1 = (const float*)d_in[12];
  const float* fcb1 = (const float*)d_in[13];
  const float* g1   = (const float*)d_in[14];
  const float* be1  = (const float*)d_in[15];

  const int E0 = in_sizes[1] / 2, E1 = in_sizes[2] / 2, E2 = in_sizes[3] / 2;
  const int ETOT = E0 + E1 + E2;

  const size_t N = NN;

  float* ws    = (float*)d_ws;
  float* sOut  = ws;                        // 3N raw out-degrees
  float* sIn   = sOut + 3 * N;              // 3N raw in-degrees
  u16*   acc16 = (u16*)(sIn + 3 * N);       // N*128 bf16
  float* stats = (float*)(acc16 + N * 128); // 512 (L0: [0..256), L1: [256..512))
  u16*   Y     = (u16*)(stats + 512);       // N*384 bf16
  float* Z     = (float*)(Y + N * 384);     // N*128 f32
  u16*   Wt0   = (u16*)(Z + N * 128);       // 3*128*1280
  u16*   Wt1   = Wt0 + 3 * 128 * 1280;      // 3*128*128
  u16*   fcWt0 = Wt1 + 3 * 128 * 128;       // 128*128
  u16*   fcWt1 = fcWt0 + 128 * 128;         // 128*128
  int*   off   = (int*)(fcWt1 + 128 * 128); // N+1
  int*   off2  = off + (NN + 1);            // N (mutable cursor copy)
  int*   aux   = off2 + NN;                 // scan aux
  int*   srt   = aux + 1536;                // ETOT

  const int NT = (NN + 127) / 128;

  // ---- preprocessing (7 dispatches) ----
  k_init<<<(6 * NN + 255) / 256, 256, 0, stream>>>(sOut, 6 * NN, stats, 512);
  k_deg_all<<<(ETOT + 255) / 256, 256, 0, stream>>>(seq, knn, dis, E0, E1, E2, sOut, sIn);

  const int nsc = NN + 1;
  const int nb  = (nsc + 255) / 256;
  k_scan1_c<<<nb, 256, 0, stream>>>(sIn, off, aux, nsc);
  k_scan2<<<1, 256, 0, stream>>>(aux, nb);
  k_scan3<<<nb, 256, 0, stream>>>(off, off2, aux, nsc);

  k_fill_all<<<(ETOT + 255) / 256, 256, 0, stream>>>(seq, knn, dis, E0, E1, E2, off2, srt);

  const int CVT_TOT = 3 * 1280 * 128 + 3 * 128 * 128 + 2 * 128 * 128;
  k_cvt_all<<<(CVT_TOT + 255) / 256, 256, 0, stream>>>(W0, W1, fcW0, fcW1, Wt0, Wt1, fcWt0, fcWt1);

  // ---- layer 0 ----
  k_gemm_pipe<1280, false><<<NT, 512, 0, stream>>>(x, Wt0, sOut, nullptr, nullptr, nullptr, Y, NN);
  k_gather<<<(NN + 3) / 4, 256, 0, stream>>>(off, srt, sIn, Y, b0, acc16);
  k_fc_mfma<<<NT, 512, 0, stream>>>(acc16, fcWt0, fcb0, Z, stats, NN);

  // ---- layer 1 (L0 BN-apply fused into gemm's cvt; affine computed in-prologue) ----
  k_gemm_pipe<128, true><<<NT, 512, 0, stream>>>(Z, Wt1, sOut, stats, g0, be0, Y, NN);
  k_gather<<<(NN + 3) / 4, 256, 0, stream>>>(off, srt, sIn, Y, b1, acc16);
  k_fc_mfma<<<NT, 512, 0, stream>>>(acc16, fcWt1, fcb1, Z, stats + 256, NN);
  k_bn_apply_f32<<<(NN * HID + 255) / 256, 256, 0, stream>>>(Z, stats + 256, g1, be1,
                                                             (float*)d_out, NN * HID, NN);
}

// Round 17
// 1086.291 us; speedup vs baseline: 1.1340x; 1.0693x over previous
//
#include <hip/hip_runtime.h>
#include <hip/hip_bf16.h>
#include <math.h>

#define NN 100000
#define HID 128
#define EPSV 1e-5f

typedef short bf16x8 __attribute__((ext_vector_type(8)));
typedef float f32x4 __attribute__((ext_vector_type(4)));
typedef unsigned short u16;

__device__ __forceinline__ u16 f2b(float f) {       // f32 -> bf16 RNE
  unsigned u = __builtin_bit_cast(unsigned, f);
  u += 0x7FFFu + ((u >> 16) & 1u);
  return (u16)(u >> 16);
}
__device__ __forceinline__ float b2f(u16 h) {
  unsigned u = ((unsigned)h) << 16;
  return __builtin_bit_cast(float, u);
}

#define AS1(p) ((__attribute__((address_space(1))) void*)(p))
#define AS3(p) ((__attribute__((address_space(3))) void*)(p))

// ---------------- fused init: zero degree arrays, stats (both layers), cursors ----------------
static __global__ void k_init(float* __restrict__ degs, int n6,
                              int* __restrict__ cur, int nc,
                              float* __restrict__ stats, int ns) {
  int i = blockIdx.x * blockDim.x + threadIdx.x;
  if (i < n6) degs[i] = 0.f;
  if (i < nc) cur[i] = 0;
  if (i < ns) stats[i] = 0.f;
}

// ---------------- fused degree histogram over all 3 edge lists ----------------
static __global__ void k_deg_all(const int* __restrict__ seq, const int* __restrict__ knn,
                                 const int* __restrict__ dis, int E0, int E1, int E2,
                                 float* __restrict__ sOut, float* __restrict__ sIn) {
  int e = blockIdx.x * blockDim.x + threadIdx.x;
  int rel, eo;
  const int *src, *dst;
  if (e < E0)            { rel = 0; eo = e;           src = seq; dst = seq + E0; }
  else if (e < E0 + E1)  { rel = 1; eo = e - E0;      src = knn; dst = knn + E1; }
  else if (e < E0+E1+E2) { rel = 2; eo = e - E0 - E1; src = dis; dst = dis + E2; }
  else return;
  atomicAdd(&sOut[(size_t)rel * NN + src[eo]], 1.f);
  atomicAdd(&sIn[(size_t)rel * NN + dst[eo]], 1.f);
}

// ---------------- exclusive scan (two-level); scan1 computes counts inline ----------------
static __global__ void k_scan1_c(const float* __restrict__ indegRaw, int* __restrict__ out,
                                 int* __restrict__ aux, int n) {   // n = NN+1
  __shared__ int s[256];
  int t = threadIdx.x, i = blockIdx.x * 256 + t;
  int v = 0;
  if (i < NN) v = (int)(indegRaw[i] + indegRaw[NN + i] + indegRaw[2 * NN + i]);
  s[t] = v; __syncthreads();
#pragma unroll
  for (int d = 1; d < 256; d <<= 1) {
    int x = (t >= d) ? s[t - d] : 0;
    __syncthreads();
    s[t] += x;
    __syncthreads();
  }
  if (i < n) out[i] = s[t] - v;
  if (t == 255) aux[blockIdx.x] = s[255];
}

static __global__ void k_scan2(int* __restrict__ aux, int nb) {
  __shared__ int s[256];
  __shared__ int carry;
  int t = threadIdx.x;
  if (t == 0) carry = 0;
  __syncthreads();
  for (int base = 0; base < nb; base += 256) {
    int i = base + t;
    int v = (i < nb) ? aux[i] : 0;
    s[t] = v; __syncthreads();
#pragma unroll
    for (int d = 1; d < 256; d <<= 1) {
      int x = (t >= d) ? s[t - d] : 0;
      __syncthreads();
      s[t] += x;
      __syncthreads();
    }
    int excl = s[t] - v + carry;
    if (i < nb) aux[i] = excl;
    int tot = s[255];
    __syncthreads();
    if (t == 0) carry += tot;
    __syncthreads();
  }
}

static __global__ void k_scan3(int* __restrict__ out, const int* __restrict__ aux, int n) {
  int i = blockIdx.x * 256 + threadIdx.x;
  if (i < n) out[i] += aux[blockIdx.x];
}

// ---------------- fused CSR fill over all 3 edge lists: srt = (src<<2)|rel ----------------
static __global__ void k_fill_all(const int* __restrict__ seq, const int* __restrict__ knn,
                                  const int* __restrict__ dis, int E0, int E1, int E2,
                                  const int* __restrict__ off, int* __restrict__ cur,
                                  int* __restrict__ srt) {
  int e = blockIdx.x * blockDim.x + threadIdx.x;
  int rel, eo;
  const int *src, *dst;
  if (e < E0)            { rel = 0; eo = e;           src = seq; dst = seq + E0; }
  else if (e < E0 + E1)  { rel = 1; eo = e - E0;      src = knn; dst = knn + E1; }
  else if (e < E0+E1+E2) { rel = 2; eo = e - E0 - E1; src = dis; dst = dis + E2; }
  else return;
  int d = dst[eo];
  int p = off[d] + atomicAdd(&cur[d], 1);
  srt[p] = (src[eo] << 2) | rel;
}

// ---------------- fused weight convert: Wt0 [384][1280], Wt1 [384][128], fcWt0/1 [128][128] ----------------
static __global__ void k_cvt_all(const float* __restrict__ W0, const float* __restrict__ W1,
                                 const float* __restrict__ fcW0, const float* __restrict__ fcW1,
                                 u16* __restrict__ Wt0, u16* __restrict__ Wt1,
                                 u16* __restrict__ fcWt0, u16* __restrict__ fcWt1) {
  const int N0 = 3 * 1280 * 128, N1 = 3 * 128 * 128, N2 = 128 * 128;
  int i = blockIdx.x * blockDim.x + threadIdx.x;
  if (i < N0) {                 // W0 [3][1280][128] -> Wt0 [(rel*128+c)][1280]
    int rel = i / (1280 * 128);
    int rem = i - rel * 1280 * 128;
    int k = rem >> 7, c = rem & 127;
    Wt0[((size_t)rel * 128 + c) * 1280 + k] = f2b(W0[i]);
  } else if (i < N0 + N1) {     // W1 [3][128][128] -> Wt1 [(rel*128+c)][128]
    int j = i - N0;
    int rel = j / (128 * 128);
    int rem = j - rel * 128 * 128;
    int k = rem >> 7, c = rem & 127;
    Wt1[((size_t)rel * 128 + c) * 128 + k] = f2b(W1[j]);
  } else if (i < N0 + N1 + N2) {
    int j = i - N0 - N1;
    int k = j >> 7, c = j & 127;
    fcWt0[c * 128 + k] = f2b(fcW0[j]);
  } else if (i < N0 + N1 + 2 * N2) {
    int j = i - N0 - N1 - N2;
    int k = j >> 7, c = j & 127;
    fcWt1[c * 128 + k] = f2b(fcW1[j]);
  }
}

// ---------------- pipelined fused MFMA GEMM (R6/R11 structure, best measured: 299 us) ----------------
// Y[row, c] = outdeg^-1/2 * (A[row,:] @ Wt[c,:]);  BM=128 x BN=384, BK=32.
// 8 waves (2m x 4n), wave tile 64x96. A staged once per tile for ALL 3 relations.
// 3 LDS buffers, 2-deep prefetch, counted vmcnt, ONE s_barrier per K-step. No setprio.
// AFFINE (layer 1): A is f32 Z; BN affine v*ab[ch]+ab[128+ch] applied during cvt,
// ab table staged to LDS in prologue so affine reads never touch vmcnt.
template<int K, bool AF32, bool AFFINE>
__global__ __launch_bounds__(512)
void k_gemm_pipe(const void* __restrict__ Av,
                 const u16* __restrict__ Wt,     // [384][K] bf16
                 const float* __restrict__ soutRaw, // [3][NN] raw out-degrees
                 const float* __restrict__ abg,  // [256] affine (AFFINE only)
                 u16* __restrict__ Y,            // [M][384] bf16
                 int M)
{
  constexpr int A_BYTES = AF32 ? (128 * 32 * 4) : (128 * 32 * 2);  // 16 KB / 8 KB
  constexpr int B_BYTES = 384 * 32 * 2;                            // 24 KB
  constexpr int BUF_U16 = (A_BYTES + B_BYTES) / 2;
  __shared__ u16 lds[3][BUF_U16];   // 120 KB (AF32) / 96 KB
  __shared__ float abl[256];        // affine table (AFFINE only)

  const int row0 = blockIdx.x * 128;
  const int t    = threadIdx.x;
  const int lane = t & 63;
  const int w    = t >> 6;          // 0..7
  const int wm   = w >> 2;          // 0..1
  const int wn   = w & 3;           // 0..3
  const int l15  = lane & 15, l4 = lane >> 4;
  const int kl   = l4 * 8;
  const int nk   = K / 32;

  int ar = row0 + w * 16 + l15;  if (ar >= M) ar = M - 1;   // clamped dup read

  const float* Af = (const float*)Av;
  const u16*   Ab = (const u16*)Av;

  const u16* gb0 = Wt + (size_t)(w * 48 +      l15) * K + kl;
  const u16* gb1 = Wt + (size_t)(w * 48 + 16 + l15) * K + kl;
  const u16* gb2 = Wt + (size_t)(w * 48 + 32 + l15) * K + kl;

  auto STAGE = [&](int buf, int k0) {
    u16* L = &lds[buf][0];
    if constexpr (AF32) {
      const float* sa = Af + (size_t)ar * K + k0 + kl;
      __builtin_amdgcn_global_load_lds(AS1(sa),     AS3(L + (w * 2048) / 2),          16, 0, 0);
      __builtin_amdgcn_global_load_lds(AS1(sa + 4), AS3(L + (w * 2048 + 1024) / 2),   16, 0, 0);
    } else {
      const u16* sa = Ab + (size_t)ar * K + k0 + kl;
      __builtin_amdgcn_global_load_lds(AS1(sa),     AS3(L + (w * 1024) / 2),          16, 0, 0);
    }
    u16* Bd = L + A_BYTES / 2;
    __builtin_amdgcn_global_load_lds(AS1(gb0 + k0), AS3(Bd + (w * 3 + 0) * 512), 16, 0, 0);
    __builtin_amdgcn_global_load_lds(AS1(gb1 + k0), AS3(Bd + (w * 3 + 1) * 512), 16, 0, 0);
    __builtin_amdgcn_global_load_lds(AS1(gb2 + k0), AS3(Bd + (w * 3 + 2) * 512), 16, 0, 0);
  };

  // affine table to LDS BEFORE staging (its vmcnt retires before the pipeline starts)
  if constexpr (AFFINE) {
    if (t < 256) abl[t] = abg[t];
  }

  f32x4 acc[4][6];
#pragma unroll
  for (int m = 0; m < 4; ++m)
#pragma unroll
    for (int n = 0; n < 6; ++n) acc[m][n] = (f32x4){0.f, 0.f, 0.f, 0.f};

  STAGE(0, 0);
  if (nk > 1) STAGE(1, 32);

  for (int k = 0; k < nk; ++k) {
    if (k + 1 < nk) {
      if constexpr (AF32) asm volatile("s_waitcnt vmcnt(5)" ::: "memory");
      else                asm volatile("s_waitcnt vmcnt(4)" ::: "memory");
    } else {
      asm volatile("s_waitcnt vmcnt(0)" ::: "memory");
    }
    __builtin_amdgcn_sched_barrier(0);
    __builtin_amdgcn_s_barrier();
    __builtin_amdgcn_sched_barrier(0);

    if (k + 2 < nk) STAGE((k + 2) % 3, (k + 2) * 32);

    const int cur = k % 3;
    const int k0 = k * 32;
    bf16x8 a[4], b[6];
    if constexpr (AF32) {
      f32x4 s1, s2, s3, s4;
      if constexpr (AFFINE) {
        s1 = *(const f32x4*)&abl[k0 + kl];            // ab  for ch j=0..3
        s2 = *(const f32x4*)&abl[k0 + kl + 4];        // ab  for ch j=4..7
        s3 = *(const f32x4*)&abl[128 + k0 + kl];      // ab2 lo
        s4 = *(const f32x4*)&abl[128 + k0 + kl + 4];  // ab2 hi
      }
      const float* Al = (const float*)&lds[cur][0];
#pragma unroll
      for (int m = 0; m < 4; ++m) {
        f32x4 lo = *(const f32x4*)&Al[(wm * 4 + m) * 512 + lane * 4];
        f32x4 hi = *(const f32x4*)&Al[(wm * 4 + m) * 512 + 256 + lane * 4];
        union { bf16x8 v; u16 u[8]; } q;
#pragma unroll
        for (int j = 0; j < 4; ++j) {
          float vlo = lo[j], vhi = hi[j];
          if constexpr (AFFINE) {
            vlo = fmaf(vlo, s1[j], s3[j]);
            vhi = fmaf(vhi, s2[j], s4[j]);
          }
          q.u[j]     = __builtin_bit_cast(u16, __float2bfloat16(vlo));
          q.u[4 + j] = __builtin_bit_cast(u16, __float2bfloat16(vhi));
        }
        a[m] = q.v;
      }
    } else {
      const u16* Al = &lds[cur][0];
#pragma unroll
      for (int m = 0; m < 4; ++m) a[m] = *(const bf16x8*)&Al[(wm * 4 + m) * 512 + lane * 8];
    }
    {
      const u16* Bl = &lds[cur][A_BYTES / 2];
#pragma unroll
      for (int n = 0; n < 6; ++n) b[n] = *(const bf16x8*)&Bl[(wn * 6 + n) * 512 + lane * 8];
    }

#pragma unroll
    for (int m = 0; m < 4; ++m)
#pragma unroll
      for (int n = 0; n < 6; ++n)
        acc[m][n] = __builtin_amdgcn_mfma_f32_16x16x32_bf16(a[m], b[n], acc[m][n], 0, 0, 0);
  }

  // epilogue: C layout col=lane&15, row=(lane>>4)*4+reg; out-degree scale inlined rsqrt
#pragma unroll
  for (int m = 0; m < 4; ++m) {
    const int rb = row0 + wm * 64 + m * 16 + l4 * 4;
#pragma unroll
    for (int j = 0; j < 4; ++j) {
      const int row = rb + j;
      if (row < M) {
        u16* yrow = Y + (size_t)row * 384;
#pragma unroll
        for (int n = 0; n < 6; ++n) {
          const int c = wn * 96 + n * 16;
          const float sc = rsqrtf(fmaxf(soutRaw[(size_t)(c >> 7) * NN + row], 1.f));
          yrow[c + l15] = f2b(acc[m][n][j] * sc);
        }
      }
    }
  }
}

// ---------------- unified CSR gather (rel packed in tag, unroll 8, inline rsqrt) ----------------
static __global__ __launch_bounds__(256)
void k_gather(const int* __restrict__ off, const int* __restrict__ srt,
              const float* __restrict__ sinRaw, const u16* __restrict__ Y,
              const float* __restrict__ b, u16* __restrict__ acc16)
{
  int d = blockIdx.x * 4 + (threadIdx.x >> 6);
  if (d >= NN) return;
  int c = (threadIdx.x & 63) * 2;
  float v0 = b[c]     + b[128 + c]     + b[256 + c];
  float v1 = b[c + 1] + b[128 + c + 1] + b[256 + c + 1];
  const float sc0 = rsqrtf(fmaxf(sinRaw[d], 1.f));
  const float sc1 = rsqrtf(fmaxf(sinRaw[NN + d], 1.f));
  const float sc2 = rsqrtf(fmaxf(sinRaw[2 * NN + d], 1.f));
  int j0 = off[d], j1 = off[d + 1];
  int j = j0;
  for (; j + 8 <= j1; j += 8) {
    unsigned uu[8];
    int rr[8];
#pragma unroll
    for (int q = 0; q < 8; ++q) {
      int tg = srt[j + q];
      rr[q] = tg & 3;
      uu[q] = *(const unsigned*)&Y[(size_t)(tg >> 2) * 384 + (size_t)rr[q] * 128 + c];
    }
#pragma unroll
    for (int q = 0; q < 8; ++q) {
      float s = (rr[q] == 0) ? sc0 : ((rr[q] == 1) ? sc1 : sc2);
      v0 = fmaf(b2f((u16)(uu[q] & 0xFFFFu)), s, v0);
      v1 = fmaf(b2f((u16)(uu[q] >> 16)), s, v1);
    }
  }
  for (; j < j1; ++j) {
    int tg = srt[j];
    int r = tg & 3;
    unsigned u = *(const unsigned*)&Y[(size_t)(tg >> 2) * 384 + (size_t)r * 128 + c];
    float s = (r == 0) ? sc0 : ((r == 1) ? sc1 : sc2);
    v0 = fmaf(b2f((u16)(u & 0xFFFFu)), s, v0);
    v1 = fmaf(b2f((u16)(u >> 16)), s, v1);
  }
  unsigned o = (unsigned)f2b(v0) | ((unsigned)f2b(v1) << 16);
  *(unsigned*)&acc16[(size_t)d * 128 + c] = o;
}

// ---------------- FC (128x128) via MFMA + fused BN-stats ----------------
static __global__ __launch_bounds__(512)
void k_fc_mfma(const u16* __restrict__ A,      // [M][128] bf16
               const u16* __restrict__ Bt,     // [128][128] bf16 (row=outcol)
               const float* __restrict__ bias,
               float* __restrict__ Z, float* __restrict__ stats, int M)
{
  __shared__ u16 Ab[4][4096];   // 32 KB
  __shared__ float sst[256];

  const int row0 = blockIdx.x * 128;
  const int t    = threadIdx.x;
  const int lane = t & 63;
  const int w    = t >> 6;
  const int wm   = w >> 2;          // 0..1
  const int wn   = w & 3;           // 0..3
  const int l15  = lane & 15, l4 = lane >> 4;
  const int kl   = l4 * 8;

  if (t < 256) sst[t] = 0.f;

  int ar = row0 + w * 16 + l15;  if (ar >= M) ar = M - 1;

  bf16x8 br[2][4];
#pragma unroll
  for (int n = 0; n < 2; ++n)
#pragma unroll
    for (int ks = 0; ks < 4; ++ks)
      br[n][ks] = *(const bf16x8*)&Bt[(size_t)(wn * 32 + n * 16 + l15) * 128 + ks * 32 + kl];

#pragma unroll
  for (int ks = 0; ks < 4; ++ks)
    __builtin_amdgcn_global_load_lds(AS1(A + (size_t)ar * 128 + ks * 32 + kl),
                                     AS3(&Ab[ks][w * 512]), 16, 0, 0);

  asm volatile("s_waitcnt vmcnt(0)" ::: "memory");
  __syncthreads();

  f32x4 acc[4][2];
#pragma unroll
  for (int m = 0; m < 4; ++m) { acc[m][0] = (f32x4){0,0,0,0}; acc[m][1] = (f32x4){0,0,0,0}; }

#pragma unroll
  for (int ks = 0; ks < 4; ++ks) {
#pragma unroll
    for (int m = 0; m < 4; ++m) {
      bf16x8 a = *(const bf16x8*)&Ab[ks][(wm * 4 + m) * 512 + lane * 8];
      acc[m][0] = __builtin_amdgcn_mfma_f32_16x16x32_bf16(a, br[0][ks], acc[m][0], 0, 0, 0);
      acc[m][1] = __builtin_amdgcn_mfma_f32_16x16x32_bf16(a, br[1][ks], acc[m][1], 0, 0, 0);
    }
  }

  float ps[2] = {0.f, 0.f}, ps2[2] = {0.f, 0.f};
#pragma unroll
  for (int m = 0; m < 4; ++m) {
    const int rb = row0 + wm * 64 + m * 16 + l4 * 4;
#pragma unroll
    for (int j = 0; j < 4; ++j) {
      const int row = rb + j;
      const bool ok = row < M;
#pragma unroll
      for (int n = 0; n < 2; ++n) {
        const int cc = wn * 32 + n * 16 + l15;
        float v = ok ? fmaxf(acc[m][n][j] + bias[cc], 0.f) : 0.f;
        if (ok) Z[(size_t)row * 128 + cc] = v;
        ps[n]  += v;
        ps2[n] += v * v;
      }
    }
  }
#pragma unroll
  for (int n = 0; n < 2; ++n) {
    ps[n]  += __shfl_xor(ps[n], 16);  ps[n]  += __shfl_xor(ps[n], 32);
    ps2[n] += __shfl_xor(ps2[n], 16); ps2[n] += __shfl_xor(ps2[n], 32);
  }
  if (l4 == 0) {
#pragma unroll
    for (int n = 0; n < 2; ++n) {
      const int cc = wn * 32 + n * 16 + l15;
      atomicAdd(&sst[cc], ps[n]);
      atomicAdd(&sst[128 + cc], ps2[n]);
    }
  }
  __syncthreads();
  if (t < 256) atomicAdd(&stats[t], sst[t]);
}

// ---------------- BatchNorm finalize / final apply ----------------
static __global__ void k_bn_finalize(const float* __restrict__ stats, int M,
                                     const float* __restrict__ g, const float* __restrict__ beta,
                                     float* __restrict__ ab) {
  int j = threadIdx.x;  // 128
  float m  = stats[j] / (float)M;
  float v  = stats[128 + j] / (float)M - m * m;
  float inv = rsqrtf(v + EPSV) * g[j];
  ab[j]       = inv;
  ab[128 + j] = beta[j] - m * inv;
}

static __global__ void k_bn_apply_f32(const float* __restrict__ Z, const float* __restrict__ ab,
                                      float* __restrict__ out, int n) {
  int i = blockIdx.x * blockDim.x + threadIdx.x;
  if (i < n) {
    int j = i & 127;
    out[i] = Z[i] * ab[j] + ab[128 + j];
  }
}

extern "C" void kernel_launch(void* const* d_in, const int* in_sizes, int n_in,
                              void* d_out, int out_size, void* d_ws, size_t ws_size,
                              hipStream_t stream)
{
  const float* x    = (const float*)d_in[0];
  const int*   seq  = (const int*)d_in[1];
  const int*   knn  = (const int*)d_in[2];
  const int*   dis  = (const int*)d_in[3];
  const float* W0   = (const float*)d_in[4];
  const float* b0   = (const float*)d_in[5];
  const float* fcW0 = (const float*)d_in[6];
  const float* fcb0 = (const float*)d_in[7];
  const float* g0   = (const float*)d_in[8];
  const float* be0  = (const float*)d_in[9];
  const float* W1   = (const float*)d_in[10];
  const float* b1   = (const float*)d_in[11];
  const float* fcW1 = (const float*)d_in[12];
  const float* fcb1 = (const float*)d_in[13];
  const float* g1   = (const float*)d_in[14];
  const float* be1  = (const float*)d_in[15];

  const int E0 = in_sizes[1] / 2, E1 = in_sizes[2] / 2, E2 = in_sizes[3] / 2;
  const int ETOT = E0 + E1 + E2;

  const size_t N = NN;

  float* ws    = (float*)d_ws;
  float* sOut  = ws;                        // 3N raw out-degrees
  float* sIn   = sOut + 3 * N;              // 3N raw in-degrees
  u16*   acc16 = (u16*)(sIn + 3 * N);       // N*128 bf16
  float* stats = (float*)(acc16 + N * 128); // 512 (L0: [0..256), L1: [256..512))
  float* ab0   = stats + 512;               // 256
  float* ab1   = ab0 + 256;                 // 256
  u16*   Y     = (u16*)(ab1 + 256);         // N*384 bf16
  float* Z     = (float*)(Y + N * 384);     // N*128 f32 (own region: gemm1 reads it)
  u16*   Wt0   = (u16*)(Z + N * 128);       // 3*128*1280
  u16*   Wt1   = Wt0 + 3 * 128 * 1280;      // 3*128*128
  u16*   fcWt0 = Wt1 + 3 * 128 * 128;       // 128*128
  u16*   fcWt1 = fcWt0 + 128 * 128;         // 128*128
  int*   off   = (int*)(fcWt1 + 128 * 128); // N+1
  int*   aux   = off + (NN + 1);            // scan aux (<=1536)
  int*   cur   = aux + 1536;                // N
  int*   srt   = cur + NN;                  // ETOT
  // total ~183 MB

  const int NT = (NN + 127) / 128;

  // ---- preprocessing (7 dispatches) ----
  k_init<<<(6 * NN + 255) / 256, 256, 0, stream>>>(sOut, 6 * NN, cur, NN, stats, 512);
  k_deg_all<<<(ETOT + 255) / 256, 256, 0, stream>>>(seq, knn, dis, E0, E1, E2, sOut, sIn);

  const int nsc = NN + 1;
  const int nb  = (nsc + 255) / 256;
  k_scan1_c<<<nb, 256, 0, stream>>>(sIn, off, aux, nsc);
  k_scan2<<<1, 256, 0, stream>>>(aux, nb);
  k_scan3<<<nb, 256, 0, stream>>>(off, aux, nsc);

  k_fill_all<<<(ETOT + 255) / 256, 256, 0, stream>>>(seq, knn, dis, E0, E1, E2, off, cur, srt);

  const int CVT_TOT = 3 * 1280 * 128 + 3 * 128 * 128 + 2 * 128 * 128;
  k_cvt_all<<<(CVT_TOT + 255) / 256, 256, 0, stream>>>(W0, W1, fcW0, fcW1, Wt0, Wt1, fcWt0, fcWt1);

  // ---- layer 0: x f32 [N,1280] -> Z f32 [N,128] (pre-BN), ab0 ----
  k_gemm_pipe<1280, true, false><<<NT, 512, 0, stream>>>(x, Wt0, sOut, nullptr, Y, NN);
  k_gather<<<(NN + 3) / 4, 256, 0, stream>>>(off, srt, sIn, Y, b0, acc16);
  k_fc_mfma<<<NT, 512, 0, stream>>>(acc16, fcWt0, fcb0, Z, stats, NN);
  k_bn_finalize<<<1, 128, 0, stream>>>(stats, NN, g0, be0, ab0);

  // ---- layer 1: gemm reads Z + applies ab0 in the cvt (BN-apply fused) ----
  k_gemm_pipe<128, true, true><<<NT, 512, 0, stream>>>(Z, Wt1, sOut, ab0, Y, NN);
  k_gather<<<(NN + 3) / 4, 256, 0, stream>>>(off, srt, sIn, Y, b1, acc16);
  k_fc_mfma<<<NT, 512, 0, stream>>>(acc16, fcWt1, fcb1, Z, stats + 256, NN);
  k_bn_finalize<<<1, 128, 0, stream>>>(stats + 256, NN, g1, be1, ab1);
  k_bn_apply_f32<<<(NN * HID + 255) / 256, 256, 0, stream>>>(Z, ab1, (float*)d_out, NN * HID);
}